// Round 11
// baseline (105.212 us; speedup 1.0000x reference)
//
#include <hip/hip_runtime.h>
#include <hip/hip_bf16.h>

// StreamingConv == GEMM: C[b,o] = sum_k A[b,k]*W[o,k]; A[256][16384], W[1024][16384] f32.
// R11: FUSED split-K. R6..R9 all land 29.7-31.7us across structurally different
// kernels -> 2-dispatch design is at its traffic+launch floor (ws slices drain to
// HBM between dispatches, reduce re-fetches them cold + launch gap). Fix: single
// kernel, grid 256 (1 block/CU, co-resident by construction), phase 1 = R8-style
// bf16-LDS gemm (NB=8, BN=128, SKB=32, XCD co-scheduling), then device-scope spin
// barrier (counter zeroed by a 256B memset node), then phase 2 = in-kernel reduce
// of the 32 bf16 slices while they are still L2/L3-hot.

#define CO    1024
#define KTOT  16384
#define BM    256
#define BN    128
#define NB    8
#define SKB   32
#define NBLK  (NB * SKB)          // 256 blocks
#define KC    (KTOT / SKB)        // 512
#define BK    32                  // k-step; bf16 row data 64B
#define KITERS (KC / BK)          // 16
#define LDA   40                  // ushort stride per LDS row (80B, padded)
#define SLICE_ELEMS (BM * CO)     // 262144 bf16 per slice

typedef __attribute__((ext_vector_type(8))) short short8;
typedef __attribute__((ext_vector_type(4))) float f32x4;
typedef __attribute__((ext_vector_type(4))) unsigned short u16x4;

__device__ __forceinline__ unsigned short f2bf(float f) {
    union { __bf16 h; unsigned short u; } c; c.h = (__bf16)f; return c.u;
}

__device__ __forceinline__ short8 pack8(f32x4 a, f32x4 b) {
    short8 r;
    r[0] = (short)f2bf(a[0]); r[1] = (short)f2bf(a[1]);
    r[2] = (short)f2bf(a[2]); r[3] = (short)f2bf(a[3]);
    r[4] = (short)f2bf(b[0]); r[5] = (short)f2bf(b[1]);
    r[6] = (short)f2bf(b[2]); r[7] = (short)f2bf(b[3]);
    return r;
}

template <bool USE_WS>
__global__ __launch_bounds__(512, 2)
void sconv_fused_v11(const float* __restrict__ A, const float* __restrict__ W,
                     float* __restrict__ out, unsigned short* __restrict__ slices,
                     unsigned int* __restrict__ ctr) {
    __shared__ __align__(16) unsigned short lA[2][BM * LDA];   // 2 x 20 KB
    __shared__ __align__(16) unsigned short lB[2][BN * LDA];   // 2 x 10 KB (60 KB)

    const int tid  = threadIdx.x;
    const int wid  = tid >> 6;
    const int lane = tid & 63;

    // decode (kb, nb) so wgid%8 == kb%8 (blocks sharing an A k-chunk -> same XCD L2)
    const int wgid = blockIdx.x;            // 0..255
    const int c  = wgid & 7;
    const int rs = wgid >> 3;               // 0..31
    const int nb = rs & 7;                  // 0..7
    const int kb = (rs >> 3) * 8 + c;       // 0..31
    const int bn = nb * BN;
    const int k0 = kb * KC;

    // ---- staging map: 16B bf16 units. A: 256x4 = 1024 units (2/thread);
    //      B: 128x4 = 512 units (1/thread).
    const int aR = tid >> 2, aG = tid & 3;          // unit0 row aR, unit1 row aR+128
    const float* Ap0 = A + (size_t)aR * KTOT + k0 + aG * 8;
    const float* Ap1 = Ap0 + (size_t)128 * KTOT;
    const int wA0 = aR * LDA + aG * 8;
    const int wA1 = wA0 + 128 * LDA;
    const int bR = tid >> 2, bG = tid & 3;
    const float* Bp = W + (size_t)(bn + bR) * KTOT + k0 + bG * 8;
    const int wB = bR * LDA + bG * 8;

#define STAGE(BUF, T) {                                                       \
        f32x4 a00 = *(const f32x4*)(Ap0 + (T) * BK);                          \
        f32x4 a01 = *(const f32x4*)(Ap0 + (T) * BK + 4);                      \
        f32x4 a10 = *(const f32x4*)(Ap1 + (T) * BK);                          \
        f32x4 a11 = *(const f32x4*)(Ap1 + (T) * BK + 4);                      \
        f32x4 b0  = *(const f32x4*)(Bp  + (T) * BK);                          \
        f32x4 b1  = *(const f32x4*)(Bp  + (T) * BK + 4);                      \
        *(short8*)&lA[BUF][wA0] = pack8(a00, a01);                            \
        *(short8*)&lA[BUF][wA1] = pack8(a10, a11);                            \
        *(short8*)&lB[BUF][wB]  = pack8(b0, b1);                              \
    }

    // ---- wave -> 64x64 sub-tile (4m x 2n wave grid over 256x128) ----
    const int wm = (wid >> 1) * 64;
    const int wn = (wid & 1) * 64;
    const int q  = lane >> 4;          // k-group (16B) of this lane
    const int fr = lane & 15;

    int offA[4], offB[4];
    #pragma unroll
    for (int mi = 0; mi < 4; ++mi) offA[mi] = (wm + mi * 16 + fr) * LDA + q * 8;
    #pragma unroll
    for (int ni = 0; ni < 4; ++ni) offB[ni] = (wn + ni * 16 + fr) * LDA + q * 8;

    f32x4 acc[4][4] = {};

#define COMPUTE(BUF) {                                                        \
        short8 bf[4];                                                         \
        _Pragma("unroll")                                                     \
        for (int ni = 0; ni < 4; ++ni)                                        \
            bf[ni] = *(const short8*)&lB[BUF][offB[ni]];                      \
        _Pragma("unroll")                                                     \
        for (int mi = 0; mi < 4; ++mi) {                                      \
            short8 af = *(const short8*)&lA[BUF][offA[mi]];                   \
            _Pragma("unroll")                                                 \
            for (int ni = 0; ni < 4; ++ni)                                    \
                acc[mi][ni] = __builtin_amdgcn_mfma_f32_16x16x32_bf16(        \
                    af, bf[ni], acc[mi][ni], 0, 0, 0);                        \
        }                                                                     \
    }

    STAGE(0, 0);
    __syncthreads();
    #pragma unroll
    for (int t = 0; t < KITERS; ++t) {
        COMPUTE(t & 1);
        if (t + 1 < KITERS) STAGE((t + 1) & 1, t + 1);
        __syncthreads();
    }
#undef STAGE
#undef COMPUTE

    // ---- epilogue. C/D 16x16x32: col = fr, row = q*4 + j.
    if (USE_WS) {
        // permuted cols within each 64-col wave region: colp = fr*4 + ni
        // (true col = ni*16 + fr); phase 2 inverts.
        unsigned short* slice = slices + (size_t)kb * SLICE_ELEMS;
        const int pbase = bn + wn + fr * 4;
        #pragma unroll
        for (int mi = 0; mi < 4; ++mi) {
            #pragma unroll
            for (int j = 0; j < 4; ++j) {
                const int r = wm + mi * 16 + q * 4 + j;
                u16x4 v;
                #pragma unroll
                for (int ni = 0; ni < 4; ++ni) v[ni] = f2bf(acc[mi][ni][j]);
                *(u16x4*)&slice[(size_t)r * CO + pbase] = v;
            }
        }

        // ---- device-scope barrier: all slices written & visible ----
        __threadfence();                 // wbl2: slice stores reach coherent point
        __syncthreads();
        if (tid == 0) {
            __hip_atomic_fetch_add(ctr, 1u, __ATOMIC_ACQ_REL, __HIP_MEMORY_SCOPE_AGENT);
            while (__hip_atomic_load(ctr, __ATOMIC_ACQUIRE, __HIP_MEMORY_SCOPE_AGENT)
                   < (unsigned int)NBLK) {
                __builtin_amdgcn_s_sleep(2);
            }
        }
        __syncthreads();

        // ---- phase 2: reduce 32 slices, invert permutation, write out ----
        // 65536 u16x4 groups total; block handles [wgid*256, wgid*256+256).
        if (tid < 256) {
            const int g = wgid * 256 + tid;
            const u16x4* base = (const u16x4*)slices;
            float s[4] = {0, 0, 0, 0};
            #pragma unroll 8
            for (int sdx = 0; sdx < SKB; ++sdx) {
                u16x4 v = base[(size_t)sdx * (SLICE_ELEMS / 4) + g];
                #pragma unroll
                for (int e = 0; e < 4; ++e) {
                    unsigned int u = ((unsigned int)v[e]) << 16;
                    s[e] += __builtin_bit_cast(float, u);
                }
            }
            #pragma unroll
            for (int e = 0; e < 4; ++e) {
                const int f  = g * 4 + e;
                const int r  = f >> 10;
                const int cp = f & 1023;
                const int p  = cp & 63;
                const int col = (cp & ~63) + (p & 3) * 16 + (p >> 2);
                out[(size_t)r * CO + col] = s[e];
            }
        }
    } else {
        #pragma unroll
        for (int mi = 0; mi < 4; ++mi)
            #pragma unroll
            for (int ni = 0; ni < 4; ++ni) {
                const int col = bn + wn + ni * 16 + fr;
                #pragma unroll
                for (int j = 0; j < 4; ++j) {
                    const int r = wm + mi * 16 + q * 4 + j;
                    unsafeAtomicAdd(out + (size_t)r * CO + col, acc[mi][ni][j]);
                }
            }
    }
}

extern "C" void kernel_launch(void* const* d_in, const int* in_sizes, int n_in,
                              void* d_out, int out_size, void* d_ws, size_t ws_size,
                              hipStream_t stream) {
    const float* A = (const float*)d_in[0];
    const float* W = (const float*)d_in[1];
    float* out = (float*)d_out;

    // ws layout: [0,256) counter region; [256, ...) bf16 slices
    const size_t ws_needed = 256 + (size_t)SKB * SLICE_ELEMS * sizeof(unsigned short);

    if (ws_size >= ws_needed) {
        unsigned int*   ctr    = (unsigned int*)d_ws;
        unsigned short* slices = (unsigned short*)((char*)d_ws + 256);
        hipMemsetAsync(d_ws, 0, 256, stream);   // zero the barrier counter
        sconv_fused_v11<true><<<NBLK, 512, 0, stream>>>(A, W, out, slices, ctr);
    } else {
        hipMemsetAsync(d_out, 0, (size_t)out_size * sizeof(float), stream);
        sconv_fused_v11<false><<<NBLK, 512, 0, stream>>>(A, W, out, nullptr, nullptr);
    }
}

// Round 12
// 30.031 us; speedup vs baseline: 3.5035x; 3.5035x over previous
//
#include <hip/hip_runtime.h>
#include <hip/hip_bf16.h>

// StreamingConv == GEMM: C[b,o] = sum_k A[b,k]*W[o,k]; A[256][16384], W[1024][16384] f32.
// R12: back to the 2-dispatch split-K champion (R6, 29.66us) + the one untried
// zero-byte lever: 2 blocks/CU at R6's traffic point. R11's fused spin-barrier
// poisoned L2 (non-coherent XCDs) - reverted. Split M (BM=128, MB=2) instead of
// N/K: grid 512 = NB(8) x SKB(32) x MB(2), bf16-in-LDS 40KB/block -> 2 blocks/CU,
// ws unchanged 16.8 MB (M-halves own disjoint slice rows). XCD swizzle co-locates
// mb-pairs (same wgid%8) so the 2x logical W reads dedup in the XCD's L2; A keeps
// kb co-location. Permuted u16x4 epilogue; reduce inverts.

#define CO    1024
#define KTOT  16384
#define BM    128                 // M rows per block (MB=2 halves)
#define BN    128
#define NB    8
#define SKB   32
#define MB    2
#define KC    (KTOT / SKB)        // 512
#define BK    32                  // k-step; bf16 row data 64B
#define KITERS (KC / BK)          // 16
#define LDA   40                  // ushort stride per LDS row (80B, padded)
#define SLICE_ELEMS (256 * CO)    // 262144 bf16 per slice (full M x CO)

typedef __attribute__((ext_vector_type(8))) short short8;
typedef __attribute__((ext_vector_type(4))) float f32x4;
typedef __attribute__((ext_vector_type(4))) unsigned short u16x4;

__device__ __forceinline__ unsigned short f2bf(float f) {
    union { __bf16 h; unsigned short u; } c; c.h = (__bf16)f; return c.u;
}

__device__ __forceinline__ short8 pack8(f32x4 a, f32x4 b) {
    short8 r;
    r[0] = (short)f2bf(a[0]); r[1] = (short)f2bf(a[1]);
    r[2] = (short)f2bf(a[2]); r[3] = (short)f2bf(a[3]);
    r[4] = (short)f2bf(b[0]); r[5] = (short)f2bf(b[1]);
    r[6] = (short)f2bf(b[2]); r[7] = (short)f2bf(b[3]);
    return r;
}

template <bool USE_WS>
__global__ __launch_bounds__(512, 4)
void sconv_gemm_v12(const float* __restrict__ A, const float* __restrict__ W,
                    float* __restrict__ out, unsigned short* __restrict__ slices) {
    __shared__ __align__(16) unsigned short lA[2][BM * LDA];   // 2 x 10 KB
    __shared__ __align__(16) unsigned short lB[2][BN * LDA];   // 2 x 10 KB (40 KB)

    const int tid  = threadIdx.x;
    const int wid  = tid >> 6;
    const int lane = tid & 63;

    // decode (kb, nb, mb) with wgid%8 == kb%8:
    //  - all 16 blocks sharing a kb (8 nb x 2 mb) -> same XCD (A chunk L2-dedup)
    //  - mb-pairs (same kb,nb) -> same XCD (W chunk L2-dedup)
    const int wgid = blockIdx.x;            // 0..511
    const int c  = wgid & 7;
    const int rs = wgid >> 3;               // 0..63
    const int mb = rs & 1;
    const int nb = (rs >> 1) & 7;
    const int kb = (rs >> 4) * 8 + c;       // 0..31
    const int bm = mb * BM;
    const int bn = nb * BN;
    const int k0 = kb * KC;

    // ---- staging map: 16B bf16 units. A: 128x4 = 512 (1/thread); B: same.
    const int sR = tid >> 2, sG = tid & 3;
    const float* Ap = A + (size_t)(bm + sR) * KTOT + k0 + sG * 8;
    const float* Bp = W + (size_t)(bn + sR) * KTOT + k0 + sG * 8;
    const int wAo = sR * LDA + sG * 8;
    const int wBo = sR * LDA + sG * 8;

#define STAGE(BUF, T) {                                                       \
        f32x4 a0 = *(const f32x4*)(Ap + (T) * BK);                            \
        f32x4 a1 = *(const f32x4*)(Ap + (T) * BK + 4);                        \
        f32x4 b0 = *(const f32x4*)(Bp + (T) * BK);                            \
        f32x4 b1 = *(const f32x4*)(Bp + (T) * BK + 4);                        \
        *(short8*)&lA[BUF][wAo] = pack8(a0, a1);                              \
        *(short8*)&lB[BUF][wBo] = pack8(b0, b1);                              \
    }

    // ---- wave -> 32M x 64N sub-tile (4m x 2n wave grid over 128x128) ----
    const int wm = (wid >> 1) * 32;
    const int wn = (wid & 1) * 64;
    const int q  = lane >> 4;          // k-group (16B) of this lane
    const int fr = lane & 15;

    int offA[2], offB[4];
    #pragma unroll
    for (int mi = 0; mi < 2; ++mi) offA[mi] = (wm + mi * 16 + fr) * LDA + q * 8;
    #pragma unroll
    for (int ni = 0; ni < 4; ++ni) offB[ni] = (wn + ni * 16 + fr) * LDA + q * 8;

    f32x4 acc[2][4] = {};

#define COMPUTE(BUF) {                                                        \
        short8 bf[4];                                                         \
        _Pragma("unroll")                                                     \
        for (int ni = 0; ni < 4; ++ni)                                        \
            bf[ni] = *(const short8*)&lB[BUF][offB[ni]];                      \
        _Pragma("unroll")                                                     \
        for (int mi = 0; mi < 2; ++mi) {                                      \
            short8 af = *(const short8*)&lA[BUF][offA[mi]];                   \
            _Pragma("unroll")                                                 \
            for (int ni = 0; ni < 4; ++ni)                                    \
                acc[mi][ni] = __builtin_amdgcn_mfma_f32_16x16x32_bf16(        \
                    af, bf[ni], acc[mi][ni], 0, 0, 0);                        \
        }                                                                     \
    }

    STAGE(0, 0);
    __syncthreads();
    #pragma unroll
    for (int t = 0; t < KITERS; ++t) {
        COMPUTE(t & 1);
        if (t + 1 < KITERS) STAGE((t + 1) & 1, t + 1);
        __syncthreads();
    }
#undef STAGE
#undef COMPUTE

    // ---- epilogue. C/D 16x16x32: col = fr, row = q*4 + j.
    if (USE_WS) {
        // permuted cols within each 64-col wave region: colp = fr*4 + ni
        // (true col = ni*16 + fr); reduce kernel inverts.
        unsigned short* slice = slices + (size_t)kb * SLICE_ELEMS;
        const int pbase = bn + wn + fr * 4;
        #pragma unroll
        for (int mi = 0; mi < 2; ++mi) {
            #pragma unroll
            for (int j = 0; j < 4; ++j) {
                const int r = bm + wm + mi * 16 + q * 4 + j;
                u16x4 v;
                #pragma unroll
                for (int ni = 0; ni < 4; ++ni) v[ni] = f2bf(acc[mi][ni][j]);
                *(u16x4*)&slice[(size_t)r * CO + pbase] = v;
            }
        }
    } else {
        #pragma unroll
        for (int mi = 0; mi < 2; ++mi)
            #pragma unroll
            for (int ni = 0; ni < 4; ++ni) {
                const int col = bn + wn + ni * 16 + fr;
                #pragma unroll
                for (int j = 0; j < 4; ++j) {
                    const int r = bm + wm + mi * 16 + q * 4 + j;
                    unsafeAtomicAdd(out + (size_t)r * CO + col, acc[mi][ni][j]);
                }
            }
    }
}

// sum 32 bf16 slices elementwise and invert the column permutation.
// u16x4 group g: r = g>>8, cp4 = (g&255)*4; for element e: cp = cp4+e,
// p = cp&63 -> fr = p>>2, ni = p&3; true col = (cp&~63) + ni*16 + fr.
__global__ __launch_bounds__(256)
void reduce_splitk_v12(const unsigned short* __restrict__ slices,
                       float* __restrict__ out) {
    const int g = blockIdx.x * 256 + threadIdx.x;    // 0..65535
    const u16x4* base = (const u16x4*)slices;
    float s[4] = {0, 0, 0, 0};
    #pragma unroll 8
    for (int sdx = 0; sdx < SKB; ++sdx) {
        u16x4 v = base[(size_t)sdx * (SLICE_ELEMS / 4) + g];
        #pragma unroll
        for (int e = 0; e < 4; ++e) {
            unsigned int u = ((unsigned int)v[e]) << 16;
            s[e] += __builtin_bit_cast(float, u);
        }
    }
    #pragma unroll
    for (int e = 0; e < 4; ++e) {
        const int f  = g * 4 + e;
        const int r  = f >> 10;
        const int cp = f & 1023;
        const int p  = cp & 63;
        const int col = (cp & ~63) + (p & 3) * 16 + (p >> 2);
        out[(size_t)r * CO + col] = s[e];
    }
}

extern "C" void kernel_launch(void* const* d_in, const int* in_sizes, int n_in,
                              void* d_out, int out_size, void* d_ws, size_t ws_size,
                              hipStream_t stream) {
    const float* A = (const float*)d_in[0];
    const float* W = (const float*)d_in[1];
    float* out = (float*)d_out;
    unsigned short* ws = (unsigned short*)d_ws;

    const size_t ws_needed = (size_t)SKB * SLICE_ELEMS * sizeof(unsigned short); // 16.8 MB

    if (ws_size >= ws_needed) {
        sconv_gemm_v12<true><<<NB * SKB * MB, 512, 0, stream>>>(A, W, out, ws);
        reduce_splitk_v12<<<SLICE_ELEMS / 4 / 256, 256, 0, stream>>>(ws, out);
    } else {
        hipMemsetAsync(d_out, 0, (size_t)out_size * sizeof(float), stream);
        sconv_gemm_v12<false><<<NB * SKB * MB, 512, 0, stream>>>(A, W, out, ws);
    }
}